// Round 10
// baseline (467.124 us; speedup 1.0000x reference)
//
#include <hip/hip_runtime.h>
#include <hip/hip_bf16.h>
#include <stdint.h>

typedef __bf16 bf16x8 __attribute__((ext_vector_type(8)));
typedef float f32x4 __attribute__((ext_vector_type(4)));
typedef float f32x16 __attribute__((ext_vector_type(16)));
typedef uint32_t u32x4 __attribute__((ext_vector_type(4)));
typedef unsigned short u16;

typedef __attribute__((address_space(1))) void as1_void;
typedef __attribute__((address_space(3))) void as3_void;

#define BAR() __builtin_amdgcn_s_barrier()
#define VMCNT(n) asm volatile("s_waitcnt vmcnt(" #n ")" ::: "memory")
#define LGKM0() asm volatile("s_waitcnt lgkmcnt(0)" ::: "memory")

__device__ __forceinline__ u16 f2bf(float f) {
  uint32_t u = __float_as_uint(f);
  u += 0x7fffu + ((u >> 16) & 1u);
  return (u16)(u >> 16);
}

// epilogue segment descriptor (uniform per block)
struct Seg {
  const u16* W;         // bf16 weight [1024,1024] (row = out col, torch W)
  const float* bias;    // [1024]
  u16* outb;            // mode 0/2 bf16 out
  float* outf;          // mode 1 fp32 out
  const float* res;     // mode 1 residual
  const float* gamma;   // mode 1 gamma
  int mode;             // 0 = bf16 rowmajor, 1 = fp32 res+gamma, 2 = Vt bf16
  int sk;               // mode2 shift
  float ascale;
};

// ---------------- prep: weight cvt (blocks 0..8191) + LN(v) (..24575) + LN(l) ----------------
__global__ __launch_bounds__(256) void prep_kernel(
    const float4* w0, const float4* w1, const float4* w2, const float4* w3,
    const float4* w4, const float4* w5, const float4* w6, const float4* w7,
    ushort4* o0, ushort4* o1, ushort4* o2, ushort4* o3,
    ushort4* o4, ushort4* o5, ushort4* o6, ushort4* o7,
    const float* v, const float* ln_v_g, const float* ln_v_b, u16* vn,
    const float* l, const float* ln_l_g, const float* ln_l_b, u16* lnm) {
  __shared__ float red[8];
  int bid = blockIdx.x, t = threadIdx.x;
  if (bid < 8192) {
    int w = bid >> 10;
    int i = ((bid & 1023) << 8) + t;
    const float4* s;
    ushort4* d;
    switch (w) {
      case 0: s = w0; d = o0; break;
      case 1: s = w1; d = o1; break;
      case 2: s = w2; d = o2; break;
      case 3: s = w3; d = o3; break;
      case 4: s = w4; d = o4; break;
      case 5: s = w5; d = o5; break;
      case 6: s = w6; d = o6; break;
      default: s = w7; d = o7; break;
    }
    float4 x = s[i];
    ushort4 o;
    o.x = f2bf(x.x); o.y = f2bf(x.y); o.z = f2bf(x.z); o.w = f2bf(x.w);
    d[i] = o;
    return;
  }
  const float *x, *g, *b;
  u16* out;
  int row;
  if (bid < 24576) {
    x = v; g = ln_v_g; b = ln_v_b; out = vn; row = bid - 8192;
  } else {
    x = l; g = ln_l_g; b = ln_l_b; out = lnm; row = bid - 24576;
  }
  const float4* xr = (const float4*)(x + (size_t)row * 1024);
  float4 vv = xr[t];
  float s = vv.x + vv.y + vv.z + vv.w;
  float s2 = vv.x * vv.x + vv.y * vv.y + vv.z * vv.z + vv.w * vv.w;
#pragma unroll
  for (int off = 1; off < 64; off <<= 1) {
    s += __shfl_xor(s, off);
    s2 += __shfl_xor(s2, off);
  }
  int wv = t >> 6;
  if ((t & 63) == 0) { red[wv] = s; red[4 + wv] = s2; }
  __syncthreads();
  s = red[0] + red[1] + red[2] + red[3];
  s2 = red[4] + red[5] + red[6] + red[7];
  float mu = s * (1.0f / 1024.0f);
  float var = s2 * (1.0f / 1024.0f) - mu * mu;
  float rstd = rsqrtf(var + 1e-5f);
  const float4 gv = ((const float4*)g)[t];
  const float4 bv = ((const float4*)b)[t];
  ushort4 o;
  o.x = f2bf((vv.x - mu) * rstd * gv.x + bv.x);
  o.y = f2bf((vv.y - mu) * rstd * gv.y + bv.y);
  o.z = f2bf((vv.z - mu) * rstd * gv.z + bv.z);
  o.w = f2bf((vv.w - mu) * rstd * gv.w + bv.w);
  ((ushort4*)out)[(size_t)row * 256 + t] = o;
}

// ================= gemm_v9: grouped 256x128 GEMM, wave tile 64x128, 1 barrier/BK=32 =================
// 4 waves, each wave = 64 rows x 128 cols (acc[4][8]); 32 MFMA + 12 ds_read_b128 per iter.
// 3-slot LDS rotation (A 16KB + B 8KB per slot = 72 KiB, 2 blocks/CU).
// STAGE = 6 global_load_lds; vmcnt ladder 12 (prologue) / 6 (steady: stages kt+1,kt+2
// outstanding -> wait retires kt+1) / 0 (tail). Swizzle f(r)=(r>>1)&3 on 16B granules:
// stored granule bank-quad (4r+p)&7 uniform -> 2 lanes/quad = conflict-free (verified r8).
__global__ __launch_bounds__(256, 2) void gemm_v9(
    const u16* __restrict__ A0, Seg s00, Seg s01, Seg s02, int mt0c, int nt0c,
    const u16* __restrict__ A1, Seg s10, Seg s11, Seg s12, int mt1c, int nt1c) {
  const int K = 1024;
  int bid = blockIdx.x;
  int nb0 = mt0c * nt0c;
  const u16* A;
  Seg sa, sb, sc;
  int mtiles, ntiles, lbid;
  if (bid < nb0) {
    A = A0; mtiles = mt0c; ntiles = nt0c; lbid = bid; sa = s00; sb = s01; sc = s02;
  } else {
    A = A1; mtiles = mt1c; ntiles = nt1c; lbid = bid - nb0; sa = s10; sb = s11; sc = s12;
  }
  int xcd = lbid & 7, q = lbid >> 3;
  int mchunk = mtiles >> 3;  // requires mtiles % 8 == 0
  int mt = xcd * mchunk + q / ntiles;
  int nt = q % ntiles;
  int m0 = mt * 256;
  int si = nt >> 3;
  Seg seg = (si == 0) ? sa : (si == 1) ? sb : sc;
  int nl0 = (nt & 7) * 128;

  int t = threadIdx.x, lane = t & 63, wv = t >> 6;
  int lr = lane & 15, lg = lane >> 4;

  __shared__ u16 SA[3][256 * 32];
  __shared__ u16 SB[3][128 * 32];

  // staging: thread t owns row r0 = t>>2 (+64/128/192), granule c0 = t&3;
  // source granule pre-swizzled (c ^ f(row)), f(r) = (r>>1)&3; f(r+64k) == f(r).
  int row0 = t >> 2, c0 = t & 3;
  int sco = (c0 ^ ((row0 >> 1) & 3)) * 8;  // u16 elems
  const u16* gA0 = A + (size_t)(m0 + row0) * K + sco;
  const u16* gB0 = seg.W + (size_t)(nl0 + row0) * K + sco;

  auto STAGE = [&](int slot, int kt) {
#pragma unroll
    for (int h = 0; h < 4; ++h)
      __builtin_amdgcn_global_load_lds(
          (const as1_void*)(gA0 + (size_t)(h * 64) * K + kt * 32),
          (as3_void*)(&SA[slot][0] + h * 2048 + t * 8), 16, 0, 0);
#pragma unroll
    for (int h = 0; h < 2; ++h)
      __builtin_amdgcn_global_load_lds(
          (const as1_void*)(gB0 + (size_t)(h * 64) * K + kt * 32),
          (as3_void*)(&SB[slot][0] + h * 2048 + t * 8), 16, 0, 0);
  };

  f32x4 acc[4][8] = {};

  STAGE(0, 0); STAGE(1, 1); STAGE(2, 2);
  VMCNT(12);  // slot0's 6 loads retired
  BAR();

  int slot = 0;
  const int NKT = K / 32;  // 32
#pragma unroll 1
  for (int kt = 0; kt < NKT; ++kt) {
    bf16x8 aX[4], bX[8];
#pragma unroll
    for (int m = 0; m < 4; ++m) {
      int row = wv * 64 + m * 16 + lr;
      aX[m] = *(const bf16x8*)(&SA[slot][0] + row * 32 + ((lg ^ ((row >> 1) & 3)) * 8));
    }
#pragma unroll
    for (int n = 0; n < 8; ++n) {
      int row = n * 16 + lr;
      bX[n] = *(const bf16x8*)(&SB[slot][0] + row * 32 + ((lg ^ ((row >> 1) & 3)) * 8));
    }
    __builtin_amdgcn_s_setprio(1);
#pragma unroll
    for (int m = 0; m < 4; ++m)
#pragma unroll
      for (int n = 0; n < 8; ++n)
        acc[m][n] = __builtin_amdgcn_mfma_f32_16x16x32_bf16(aX[m], bX[n], acc[m][n], 0, 0, 0);
    __builtin_amdgcn_s_setprio(0);
    LGKM0();                                   // all ds_reads retired
    if (kt + 2 < NKT) { VMCNT(6); }            // stage kt+1 retired; kt+2 may fly
    else if (kt + 1 < NKT) { VMCNT(0); }       // last in-flight stage must land
    BAR();                                     // single barrier: both hazards
    if (kt + 3 < NKT) STAGE(slot, kt + 3);     // overwrite just-read slot
    slot = (slot == 2) ? 0 : slot + 1;
  }

  // epilogue: per-wave 64x128, D layout col = lane&15, row = lg*4 + r
  int rowb = m0 + wv * 64 + lg * 4;
#pragma unroll
  for (int m = 0; m < 4; ++m) {
#pragma unroll
    for (int n = 0; n < 8; ++n) {
      int scol = nl0 + n * 16 + lr;
      float bcol = seg.bias[scol];
      int row = rowb + m * 16;
      if (seg.mode == 2) {
        int bb = row >> seg.sk;
        int ss = row & ((1 << seg.sk) - 1);
        int h = scol >> 6, d = scol & 63;
        ushort4 o;
        o.x = f2bf(acc[m][n][0] + bcol);
        o.y = f2bf(acc[m][n][1] + bcol);
        o.z = f2bf(acc[m][n][2] + bcol);
        o.w = f2bf(acc[m][n][3] + bcol);
        *(ushort4*)(seg.outb + ((((size_t)bb * 16 + h) * 64 + d) << seg.sk) + ss) = o;
      } else if (seg.mode == 0) {
#pragma unroll
        for (int r = 0; r < 4; ++r)
          seg.outb[(size_t)(row + r) * 1024 + scol] = f2bf((acc[m][n][r] + bcol) * seg.ascale);
      } else {
#pragma unroll
        for (int r = 0; r < 4; ++r) {
          size_t idx = (size_t)(row + r) * 1024 + scol;
          seg.outf[idx] = seg.res[idx] + seg.gamma[scol] * (acc[m][n][r] + bcol);
        }
      }
    }
  }
}

// ---------------- merged flash attention: v2l blocks [0, nb0), l2v blocks [nb0, ...) ----------------
// Swapped QK^T 32x32, in-reg softmax, LDS K/V double-buffer. ctx written IN-PLACE over Q.
__global__ __launch_bounds__(256, 4) void attn2_kernel(
    const u16* __restrict__ Q0, const u16* __restrict__ K0,
    const u16* __restrict__ V0, u16* __restrict__ C0, int Sq0, int Sk0, int nqs0, int nb0,
    const u16* __restrict__ Q1, const u16* __restrict__ K1,
    const u16* __restrict__ V1, u16* __restrict__ C1, int Sq1, int Sk1, int nqs1) {
  int bid = blockIdx.x;
  const u16 *Q, *Kmat, *Vt;
  u16* ctx;
  int Sq, Sk, nq_shift, f;
  if (bid < nb0) {
    Q = Q0; Kmat = K0; Vt = V0; ctx = C0; Sq = Sq0; Sk = Sk0; nq_shift = nqs0; f = bid;
  } else {
    Q = Q1; Kmat = K1; Vt = V1; ctx = C1; Sq = Sq1; Sk = Sk1; nq_shift = nqs1; f = bid - nb0;
  }
  int xcd = f & 7, slot = f >> 3;
  int group = xcd * 16 + (slot >> nq_shift);
  int qt = slot & ((1 << nq_shift) - 1);
  int b = group >> 4, h = group & 15;
  int t = threadIdx.x, lane = t & 63, wv = t >> 6;
  int l31 = lane & 31, hi = lane >> 5;

  __shared__ u16 Ks[2][64 * 64];
  __shared__ u16 Vs[2][64 * 64];

  int q0 = qt * 128 + wv * 32;
  const u16* Qb = Q + (size_t)(b * Sq + q0 + l31) * 1024 + h * 64 + hi * 8;
  bf16x8 qf[4];
#pragma unroll
  for (int ds = 0; ds < 4; ++ds) qf[ds] = *(const bf16x8*)(Qb + ds * 16);

  int trow = t >> 3, tc = t & 7;
  int sc = (tc ^ (trow & 7)) * 8;
  const u16* gk = Kmat + (size_t)(b * Sk + trow) * 1024 + h * 64 + sc;
  const u16* gv = Vt + (size_t)((b * 16 + h) * 64 + trow) * Sk + sc;

  auto STAGE = [&](int buf, int kt) {
    const u16* k0 = gk + (size_t)(kt * 64) * 1024;
    const u16* v0 = gv + kt * 64;
    __builtin_amdgcn_global_load_lds((const as1_void*)k0, (as3_void*)(Ks[buf] + t * 8), 16, 0, 0);
    __builtin_amdgcn_global_load_lds((const as1_void*)(k0 + (size_t)32 * 1024), (as3_void*)(Ks[buf] + 2048 + t * 8), 16, 0, 0);
    __builtin_amdgcn_global_load_lds((const as1_void*)v0, (as3_void*)(Vs[buf] + t * 8), 16, 0, 0);
    __builtin_amdgcn_global_load_lds((const as1_void*)(v0 + (size_t)32 * Sk), (as3_void*)(Vs[buf] + 2048 + t * 8), 16, 0, 0);
  };

  STAGE(0, 0);
  __syncthreads();

  f32x16 acc0 = {}, acc1 = {};
  float m_run = -1e30f, l_run = 0.f;
  int sw = l31 & 7;

  int nt = Sk >> 6;
  for (int kt = 0; kt < nt; ++kt) {
    int cur = kt & 1;
    if (kt + 1 < nt) STAGE(cur ^ 1, kt + 1);
    const u16* kb = Ks[cur];
    f32x16 s0v = {}, s1v = {};
    __builtin_amdgcn_s_setprio(1);
#pragma unroll
    for (int ds = 0; ds < 4; ++ds) {
      int blk = 2 * ds + hi;
      bf16x8 ka0 = *(const bf16x8*)(kb + l31 * 64 + ((blk ^ sw) * 8));
      bf16x8 ka1 = *(const bf16x8*)(kb + (32 + l31) * 64 + ((blk ^ sw) * 8));
      s0v = __builtin_amdgcn_mfma_f32_32x32x16_bf16(ka0, qf[ds], s0v, 0, 0, 0);
      s1v = __builtin_amdgcn_mfma_f32_32x32x16_bf16(ka1, qf[ds], s1v, 0, 0, 0);
    }
    __builtin_amdgcn_s_setprio(0);
    float mx = s0v[0];
#pragma unroll
    for (int i = 1; i < 16; ++i) mx = fmaxf(mx, s0v[i]);
#pragma unroll
    for (int i = 0; i < 16; ++i) mx = fmaxf(mx, s1v[i]);
    mx = fmaxf(mx, __shfl_xor(mx, 32));
    if (__any(mx > m_run + 8.f)) {
      float mnew = fmaxf(m_run, mx);
      float fac = __builtin_amdgcn_exp2f(m_run - mnew);
#pragma unroll
      for (int r = 0; r < 16; ++r) {
        int src = (r & 3) + 8 * (r >> 2) + 4 * hi;
        float fr = __shfl(fac, src);
        acc0[r] *= fr;
        acc1[r] *= fr;
      }
      l_run *= fac;
      m_run = mnew;
    }
    float sum = 0.f;
#pragma unroll
    for (int i = 0; i < 16; ++i) {
      s0v[i] = __builtin_amdgcn_exp2f(s0v[i] - m_run);
      sum += s0v[i];
    }
#pragma unroll
    for (int i = 0; i < 16; ++i) {
      s1v[i] = __builtin_amdgcn_exp2f(s1v[i] - m_run);
      sum += s1v[i];
    }
    sum += __shfl_xor(sum, 32);
    l_run += sum;
    bf16x8 pa[4];
#pragma unroll
    for (int g = 0; g < 2; ++g) {
      const f32x16& s = g ? s1v : s0v;
#pragma unroll
      for (int half = 0; half < 2; ++half) {
        int o = half * 8;
        uint32_t a0, a1, b0, b1;
        asm("v_cvt_pk_bf16_f32 %0, %1, %2" : "=v"(a0) : "v"(s[o + 0]), "v"(s[o + 1]));
        asm("v_cvt_pk_bf16_f32 %0, %1, %2" : "=v"(a1) : "v"(s[o + 2]), "v"(s[o + 3]));
        asm("v_cvt_pk_bf16_f32 %0, %1, %2" : "=v"(b0) : "v"(s[o + 4]), "v"(s[o + 5]));
        asm("v_cvt_pk_bf16_f32 %0, %1, %2" : "=v"(b1) : "v"(s[o + 6]), "v"(s[o + 7]));
        asm("v_permlane32_swap_b32 %0, %1" : "+v"(a0), "+v"(b0));
        asm("v_permlane32_swap_b32 %0, %1" : "+v"(a1), "+v"(b1));
        u32x4 w;
        w[0] = a0; w[1] = a1; w[2] = b0; w[3] = b1;
        pa[g * 2 + half] = __builtin_bit_cast(bf16x8, w);
      }
    }
    const u16* vb = Vs[cur];
    __builtin_amdgcn_s_setprio(1);
#pragma unroll
    for (int ks = 0; ks < 4; ++ks) {
      int blk = 2 * ks + hi;
      bf16x8 vf0 = *(const bf16x8*)(vb + l31 * 64 + ((blk ^ sw) * 8));
      bf16x8 vf1 = *(const bf16x8*)(vb + (32 + l31) * 64 + ((blk ^ sw) * 8));
      acc0 = __builtin_amdgcn_mfma_f32_32x32x16_bf16(pa[ks], vf0, acc0, 0, 0, 0);
      acc1 = __builtin_amdgcn_mfma_f32_32x32x16_bf16(pa[ks], vf1, acc1, 0, 0, 0);
    }
    __builtin_amdgcn_s_setprio(0);
    __syncthreads();
  }
  float linv = 1.0f / l_run;
  u16* cb = ctx + (size_t)(b * Sq + q0) * 1024 + h * 64;
#pragma unroll
  for (int r = 0; r < 16; ++r) {
    int src = (r & 3) + 8 * (r >> 2) + 4 * hi;
    float li = __shfl(linv, src);
    cb[(size_t)src * 1024 + l31] = f2bf(acc0[r] * li);
    cb[(size_t)src * 1024 + 32 + l31] = f2bf(acc1[r] * li);
  }
}

extern "C" void kernel_launch(void* const* d_in, const int* in_sizes, int n_in,
                              void* d_out, int out_size, void* d_ws, size_t ws_size,
                              hipStream_t stream) {
  const float* v = (const float*)d_in[0];
  const float* l = (const float*)d_in[1];
  const float* ln_v_g = (const float*)d_in[2];
  const float* ln_v_b = (const float*)d_in[3];
  const float* ln_l_g = (const float*)d_in[4];
  const float* ln_l_b = (const float*)d_in[5];
  const float* gamma_v = (const float*)d_in[6];
  const float* gamma_l = (const float*)d_in[7];
  const float* Wf[8];
  const float* Bf[8];
  for (int i = 0; i < 8; ++i) {
    Wf[i] = (const float*)d_in[8 + 2 * i];
    Bf[i] = (const float*)d_in[9 + 2 * i];
  }
  float* v_out = (float*)d_out;
  float* l_out = v_out + (size_t)16384 * 1024;

  char* p = (char*)d_ws;
  auto alloc = [&](size_t bytes) {
    char* r = p;
    p += (bytes + 255) & ~(size_t)255;
    return r;
  };
  u16* Wbf[8];
  for (int i = 0; i < 8; ++i) Wbf[i] = (u16*)alloc((size_t)1024 * 1024 * 2);
  u16* vn   = (u16*)alloc((size_t)16384 * 1024 * 2);  // LN(v)
  u16* lnm  = (u16*)alloc((size_t)4096 * 1024 * 2);   // LN(l)
  u16* bufA = (u16*)alloc((size_t)16384 * 1024 * 2);  // Q_v2l -> ctx_v (in-place)
  u16* bufB = (u16*)alloc((size_t)4096 * 1024 * 2);   // Q_l2v -> ctx_l (in-place)
  u16* bufC = (u16*)alloc((size_t)4096 * 1024 * 2);   // Vt_v2l
  u16* bufD = (u16*)alloc((size_t)16384 * 1024 * 2);  // Vt_l2v
  u16* bufF = (u16*)alloc((size_t)4096 * 1024 * 2);   // K_v2l
  u16* bufG = (u16*)alloc((size_t)16384 * 1024 * 2);  // K_l2v

  const float QSC = 0.125f * 1.4426950408889634f;  // 1/sqrt(64) * log2(e)
  Seg zs = {};

  prep_kernel<<<dim3(28672), 256, 0, stream>>>(
      (const float4*)Wf[0], (const float4*)Wf[1], (const float4*)Wf[2], (const float4*)Wf[3],
      (const float4*)Wf[4], (const float4*)Wf[5], (const float4*)Wf[6], (const float4*)Wf[7],
      (ushort4*)Wbf[0], (ushort4*)Wbf[1], (ushort4*)Wbf[2], (ushort4*)Wbf[3],
      (ushort4*)Wbf[4], (ushort4*)Wbf[5], (ushort4*)Wbf[6], (ushort4*)Wbf[7],
      v, ln_v_g, ln_v_b, vn, l, ln_l_g, ln_l_b, lnm);

  // grouped GEMM #1: trio0 on lnm (Q_l2v | K_v2l | Vt_v2l), trio1 on vn (Q_v2l | K_l2v | Vt_l2v)
  {
    Seg a = {Wbf[4], Bf[4], bufB, nullptr, nullptr, nullptr, 0, 0, QSC};
    Seg b = {Wbf[1], Bf[1], bufF, nullptr, nullptr, nullptr, 0, 0, 1.0f};
    Seg c = {Wbf[2], Bf[2], bufC, nullptr, nullptr, nullptr, 2, 9, 1.0f};
    Seg q = {Wbf[0], Bf[0], bufA, nullptr, nullptr, nullptr, 0, 0, QSC};
    Seg k = {Wbf[5], Bf[5], bufG, nullptr, nullptr, nullptr, 0, 0, 1.0f};
    Seg vv = {Wbf[6], Bf[6], bufD, nullptr, nullptr, nullptr, 2, 11, 1.0f};
    gemm_v9<<<dim3(16 * 24 + 64 * 24), 256, 0, stream>>>(lnm, a, b, c, 16, 24,
                                                         vn, q, k, vv, 64, 24);
  }
  // merged attention: v2l (2048 blocks) + l2v (512 blocks), ctx in-place over Q
  attn2_kernel<<<dim3(2048 + 512), 256, 0, stream>>>(
      bufA, bufF, bufC, bufA, 2048, 512, 4, 2048,
      bufB, bufG, bufD, bufB, 512, 2048, 2);
  // grouped GEMM #2: O-proj v (ctx_v) + O-proj l (ctx_l), fused residual epilogues
  {
    Seg ov = {Wbf[3], Bf[3], nullptr, v_out, v, gamma_v, 1, 0, 1.0f};
    Seg ol = {Wbf[7], Bf[7], nullptr, l_out, l, gamma_l, 1, 0, 1.0f};
    gemm_v9<<<dim3(64 * 8 + 16 * 8), 256, 0, stream>>>(bufA, ov, zs, zs, 64, 8,
                                                       bufB, ol, zs, zs, 16, 8);
  }
}

// Round 11
// 419.581 us; speedup vs baseline: 1.1133x; 1.1133x over previous
//
#include <hip/hip_runtime.h>
#include <hip/hip_bf16.h>
#include <stdint.h>

typedef __bf16 bf16x8 __attribute__((ext_vector_type(8)));
typedef float f32x4 __attribute__((ext_vector_type(4)));
typedef float f32x16 __attribute__((ext_vector_type(16)));
typedef uint32_t u32x4 __attribute__((ext_vector_type(4)));
typedef unsigned short u16;

typedef __attribute__((address_space(1))) void as1_void;
typedef __attribute__((address_space(3))) void as3_void;

#define BAR() __builtin_amdgcn_s_barrier()
#define VMCNT(n) asm volatile("s_waitcnt vmcnt(" #n ")" ::: "memory")
#define LGKM0() asm volatile("s_waitcnt lgkmcnt(0)" ::: "memory")

__device__ __forceinline__ u16 f2bf(float f) {
  uint32_t u = __float_as_uint(f);
  u += 0x7fffu + ((u >> 16) & 1u);
  return (u16)(u >> 16);
}

// epilogue segment descriptor (uniform per block)
struct Seg {
  const u16* W;         // bf16 weight [1024,1024] (row = out col, torch W)
  const float* bias;    // [1024]
  u16* outb;            // mode 0/2 bf16 out
  float* outf;          // mode 1 fp32 out
  const float* res;     // mode 1 residual
  const float* gamma;   // mode 1 gamma
  int mode;             // 0 = bf16 rowmajor, 1 = fp32 res+gamma, 2 = Vt bf16
  int sk;               // mode2 shift
  float ascale;
};

// ---------------- fp32 -> bf16 convert (all 8 weights, one dispatch) ----------------
__global__ __launch_bounds__(256) void cvt8_kernel(
    const float4* s0, const float4* s1, const float4* s2, const float4* s3,
    const float4* s4, const float4* s5, const float4* s6, const float4* s7,
    ushort4* d0, ushort4* d1, ushort4* d2, ushort4* d3,
    ushort4* d4, ushort4* d5, ushort4* d6, ushort4* d7) {
  const float4* s; ushort4* d;
  switch (blockIdx.y) {
    case 0: s = s0; d = d0; break;
    case 1: s = s1; d = d1; break;
    case 2: s = s2; d = d2; break;
    case 3: s = s3; d = d3; break;
    case 4: s = s4; d = d4; break;
    case 5: s = s5; d = d5; break;
    case 6: s = s6; d = d6; break;
    default: s = s7; d = d7; break;
  }
  int i = blockIdx.x * 256 + threadIdx.x;
  float4 v = s[i];
  ushort4 o;
  o.x = f2bf(v.x); o.y = f2bf(v.y); o.z = f2bf(v.z); o.w = f2bf(v.w);
  d[i] = o;
}

// ---------------- layernorm fp32 -> bf16, D=1024 ----------------
__global__ __launch_bounds__(256) void ln_kernel(const float* __restrict__ x,
                                                 const float* __restrict__ g,
                                                 const float* __restrict__ b,
                                                 u16* __restrict__ out) {
  int row = blockIdx.x;
  int t = threadIdx.x;
  const float4* xr = (const float4*)(x + (size_t)row * 1024);
  float4 v = xr[t];
  float s = v.x + v.y + v.z + v.w;
  float s2 = v.x * v.x + v.y * v.y + v.z * v.z + v.w * v.w;
#pragma unroll
  for (int off = 1; off < 64; off <<= 1) {
    s += __shfl_xor(s, off);
    s2 += __shfl_xor(s2, off);
  }
  __shared__ float red[8];
  int wv = t >> 6;
  if ((t & 63) == 0) { red[wv] = s; red[4 + wv] = s2; }
  __syncthreads();
  s = red[0] + red[1] + red[2] + red[3];
  s2 = red[4] + red[5] + red[6] + red[7];
  float mu = s * (1.0f / 1024.0f);
  float var = s2 * (1.0f / 1024.0f) - mu * mu;
  float rstd = rsqrtf(var + 1e-5f);
  const float4 gv = ((const float4*)g)[t];
  const float4 bv = ((const float4*)b)[t];
  ushort4 o;
  o.x = f2bf((v.x - mu) * rstd * gv.x + bv.x);
  o.y = f2bf((v.y - mu) * rstd * gv.y + bv.y);
  o.z = f2bf((v.z - mu) * rstd * gv.z + bv.z);
  o.w = f2bf((v.w - mu) * rstd * gv.w + bv.w);
  ((ushort4*)out)[(size_t)row * 256 + t] = o;
}

// ================= gemm_v8: grouped 128x128 GEMM, single barrier per BK=32 =================
// Two trios (A, 3 segs, mtiles, ntiles); grid = mt0c*nt0c + mt1c*nt1c.
// 3-slot LDS rotation (48 KiB, 3 blocks/CU), stage kt+3 after the barrier.
// Hazards: (1) readers of slot kt%3 finish before BAR -> overwrite after BAR safe.
//          (2) VMCNT(4) before BAR: outstanding = stages kt+1,kt+2 (8 loads) ->
//              oldest 4 (stage kt+1) retired -> slot (kt+1)%3 ready for next iter.
// Swizzle key f(r) = (r>>1)&3: stored granule bank-quad (4r+p)&7 uniform (2 lanes/quad).
__global__ __launch_bounds__(256, 3) void gemm_v8(
    const u16* __restrict__ A0, Seg s00, Seg s01, Seg s02, int mt0c, int nt0c,
    const u16* __restrict__ A1, Seg s10, Seg s11, Seg s12, int mt1c, int nt1c) {
  const int K = 1024;
  int bid = blockIdx.x;
  int nb0 = mt0c * nt0c;
  const u16* A;
  Seg sa, sb, sc;
  int mtiles, ntiles, lbid;
  if (bid < nb0) {
    A = A0; mtiles = mt0c; ntiles = nt0c; lbid = bid; sa = s00; sb = s01; sc = s02;
  } else {
    A = A1; mtiles = mt1c; ntiles = nt1c; lbid = bid - nb0; sa = s10; sb = s11; sc = s12;
  }
  int xcd = lbid & 7, q = lbid >> 3;
  int mchunk = mtiles >> 3;  // requires mtiles % 8 == 0
  int mt = xcd * mchunk + q / ntiles;
  int nt = q % ntiles;
  int m0 = mt * 128;
  int si = nt >> 3;
  Seg seg = (si == 0) ? sa : (si == 1) ? sb : sc;
  int nl0 = (nt & 7) * 128;

  int t = threadIdx.x, lane = t & 63, wv = t >> 6;
  int wr = wv >> 1, wc = wv & 1;
  int lr = lane & 15, lg = lane >> 4;

  __shared__ u16 SA[3][128 * 32];
  __shared__ u16 SB[3][128 * 32];

  // staging: thread t owns rows (t>>2), (t>>2)+64, granule t&3; source granule
  // pre-swizzled (c ^ f(row)), f(r) = (r>>1)&3; f(row+64) == f(row).
  int row0 = t >> 2, c0 = t & 3;
  int sco = (c0 ^ ((row0 >> 1) & 3)) * 8;  // u16 elems
  const u16* gA0 = A + (size_t)(m0 + row0) * K + sco;
  const u16* gB0 = seg.W + (size_t)(nl0 + row0) * K + sco;

  auto STAGE = [&](int slot, int kt) {
    __builtin_amdgcn_global_load_lds((const as1_void*)(gA0 + kt * 32),
                                     (as3_void*)(&SA[slot][0] + t * 8), 16, 0, 0);
    __builtin_amdgcn_global_load_lds((const as1_void*)(gA0 + (size_t)64 * K + kt * 32),
                                     (as3_void*)(&SA[slot][0] + 2048 + t * 8), 16, 0, 0);
    __builtin_amdgcn_global_load_lds((const as1_void*)(gB0 + kt * 32),
                                     (as3_void*)(&SB[slot][0] + t * 8), 16, 0, 0);
    __builtin_amdgcn_global_load_lds((const as1_void*)(gB0 + (size_t)64 * K + kt * 32),
                                     (as3_void*)(&SB[slot][0] + 2048 + t * 8), 16, 0, 0);
  };

  f32x4 acc[4][4] = {};

  STAGE(0, 0); STAGE(1, 1); STAGE(2, 2);
  VMCNT(8);  // slot0's 4 loads retired
  BAR();

  int slot = 0;
  const int NKT = K / 32;  // 32
#pragma unroll 1
  for (int kt = 0; kt < NKT; ++kt) {
    bf16x8 aX[4], bX[4];
#pragma unroll
    for (int m = 0; m < 4; ++m) {
      int row = wr * 64 + m * 16 + lr;
      aX[m] = *(const bf16x8*)(&SA[slot][0] + row * 32 + ((lg ^ ((row >> 1) & 3)) * 8));
    }
#pragma unroll
    for (int n = 0; n < 4; ++n) {
      int row = wc * 64 + n * 16 + lr;
      bX[n] = *(const bf16x8*)(&SB[slot][0] + row * 32 + ((lg ^ ((row >> 1) & 3)) * 8));
    }
    __builtin_amdgcn_s_setprio(1);
#pragma unroll
    for (int m = 0; m < 4; ++m)
#pragma unroll
      for (int n = 0; n < 4; ++n)
        acc[m][n] = __builtin_amdgcn_mfma_f32_16x16x32_bf16(aX[m], bX[n], acc[m][n], 0, 0, 0);
    __builtin_amdgcn_s_setprio(0);
    LGKM0();                                   // all my ds_reads retired (drained by MFMA deps already)
    if (kt + 2 < NKT) { VMCNT(4); }            // stage(kt+1) retired; stage(kt+2) may fly
    else if (kt + 1 < NKT) { VMCNT(0); }       // last in-flight stage must land
    BAR();                                     // single barrier: covers both hazards
    if (kt + 3 < NKT) STAGE(slot, kt + 3);     // overwrite just-read slot
    slot = (slot == 2) ? 0 : slot + 1;
  }

  // epilogue: per-wave 64x64, D layout col = lane&15, row = (lane>>4)*4 + r
  int rowb = m0 + wr * 64 + (lane >> 4) * 4;
#pragma unroll
  for (int m = 0; m < 4; ++m) {
#pragma unroll
    for (int n = 0; n < 4; ++n) {
      int scol = nl0 + wc * 64 + n * 16 + lr;
      float bcol = seg.bias[scol];
      int row = rowb + m * 16;
      if (seg.mode == 2) {
        int bb = row >> seg.sk;
        int ss = row & ((1 << seg.sk) - 1);
        int h = scol >> 6, d = scol & 63;
        ushort4 o;
        o.x = f2bf(acc[m][n][0] + bcol);
        o.y = f2bf(acc[m][n][1] + bcol);
        o.z = f2bf(acc[m][n][2] + bcol);
        o.w = f2bf(acc[m][n][3] + bcol);
        *(ushort4*)(seg.outb + ((((size_t)bb * 16 + h) * 64 + d) << seg.sk) + ss) = o;
      } else if (seg.mode == 0) {
#pragma unroll
        for (int r = 0; r < 4; ++r)
          seg.outb[(size_t)(row + r) * 1024 + scol] = f2bf((acc[m][n][r] + bcol) * seg.ascale);
      } else {
#pragma unroll
        for (int r = 0; r < 4; ++r) {
          size_t idx = (size_t)(row + r) * 1024 + scol;
          seg.outf[idx] = seg.res[idx] + seg.gamma[scol] * (acc[m][n][r] + bcol);
        }
      }
    }
  }
}

// ---------------- merged flash attention: LONG l2v blocks [0, nb0) FIRST, v2l after ----------------
// Long-chain blocks (32 k-tiles) dispatched first so they overlap the short v2l bulk
// instead of forming a serial tail. Swapped QK^T 32x32, in-reg softmax, LDS K/V
// double-buffer. ctx written IN-PLACE over Q.
__global__ __launch_bounds__(256, 4) void attn2_kernel(
    const u16* __restrict__ Q0, const u16* __restrict__ K0,
    const u16* __restrict__ V0, u16* __restrict__ C0, int Sq0, int Sk0, int nqs0, int nb0,
    const u16* __restrict__ Q1, const u16* __restrict__ K1,
    const u16* __restrict__ V1, u16* __restrict__ C1, int Sq1, int Sk1, int nqs1) {
  int bid = blockIdx.x;
  const u16 *Q, *Kmat, *Vt;
  u16* ctx;
  int Sq, Sk, nq_shift, f;
  if (bid < nb0) {
    Q = Q0; Kmat = K0; Vt = V0; ctx = C0; Sq = Sq0; Sk = Sk0; nq_shift = nqs0; f = bid;
  } else {
    Q = Q1; Kmat = K1; Vt = V1; ctx = C1; Sq = Sq1; Sk = Sk1; nq_shift = nqs1; f = bid - nb0;
  }
  int xcd = f & 7, slot = f >> 3;
  int group = xcd * 16 + (slot >> nq_shift);
  int qt = slot & ((1 << nq_shift) - 1);
  int b = group >> 4, h = group & 15;
  int t = threadIdx.x, lane = t & 63, wv = t >> 6;
  int l31 = lane & 31, hi = lane >> 5;

  __shared__ u16 Ks[2][64 * 64];
  __shared__ u16 Vs[2][64 * 64];

  int q0 = qt * 128 + wv * 32;
  const u16* Qb = Q + (size_t)(b * Sq + q0 + l31) * 1024 + h * 64 + hi * 8;
  bf16x8 qf[4];
#pragma unroll
  for (int ds = 0; ds < 4; ++ds) qf[ds] = *(const bf16x8*)(Qb + ds * 16);

  int trow = t >> 3, tc = t & 7;
  int sc = (tc ^ (trow & 7)) * 8;
  const u16* gk = Kmat + (size_t)(b * Sk + trow) * 1024 + h * 64 + sc;
  const u16* gv = Vt + (size_t)((b * 16 + h) * 64 + trow) * Sk + sc;

  auto STAGE = [&](int buf, int kt) {
    const u16* k0 = gk + (size_t)(kt * 64) * 1024;
    const u16* v0 = gv + kt * 64;
    __builtin_amdgcn_global_load_lds((const as1_void*)k0, (as3_void*)(Ks[buf] + t * 8), 16, 0, 0);
    __builtin_amdgcn_global_load_lds((const as1_void*)(k0 + (size_t)32 * 1024), (as3_void*)(Ks[buf] + 2048 + t * 8), 16, 0, 0);
    __builtin_amdgcn_global_load_lds((const as1_void*)v0, (as3_void*)(Vs[buf] + t * 8), 16, 0, 0);
    __builtin_amdgcn_global_load_lds((const as1_void*)(v0 + (size_t)32 * Sk), (as3_void*)(Vs[buf] + 2048 + t * 8), 16, 0, 0);
  };

  STAGE(0, 0);
  __syncthreads();

  f32x16 acc0 = {}, acc1 = {};
  float m_run = -1e30f, l_run = 0.f;
  int sw = l31 & 7;

  int nt = Sk >> 6;
  for (int kt = 0; kt < nt; ++kt) {
    int cur = kt & 1;
    if (kt + 1 < nt) STAGE(cur ^ 1, kt + 1);
    const u16* kb = Ks[cur];
    f32x16 s0v = {}, s1v = {};
    __builtin_amdgcn_s_setprio(1);
#pragma unroll
    for (int ds = 0; ds < 4; ++ds) {
      int blk = 2 * ds + hi;
      bf16x8 ka0 = *(const bf16x8*)(kb + l31 * 64 + ((blk ^ sw) * 8));
      bf16x8 ka1 = *(const bf16x8*)(kb + (32 + l31) * 64 + ((blk ^ sw) * 8));
      s0v = __builtin_amdgcn_mfma_f32_32x32x16_bf16(ka0, qf[ds], s0v, 0, 0, 0);
      s1v = __builtin_amdgcn_mfma_f32_32x32x16_bf16(ka1, qf[ds], s1v, 0, 0, 0);
    }
    __builtin_amdgcn_s_setprio(0);
    float mx = s0v[0];
#pragma unroll
    for (int i = 1; i < 16; ++i) mx = fmaxf(mx, s0v[i]);
#pragma unroll
    for (int i = 0; i < 16; ++i) mx = fmaxf(mx, s1v[i]);
    mx = fmaxf(mx, __shfl_xor(mx, 32));
    if (__any(mx > m_run + 8.f)) {
      float mnew = fmaxf(m_run, mx);
      float fac = __builtin_amdgcn_exp2f(m_run - mnew);
#pragma unroll
      for (int r = 0; r < 16; ++r) {
        int src = (r & 3) + 8 * (r >> 2) + 4 * hi;
        float fr = __shfl(fac, src);
        acc0[r] *= fr;
        acc1[r] *= fr;
      }
      l_run *= fac;
      m_run = mnew;
    }
    float sum = 0.f;
#pragma unroll
    for (int i = 0; i < 16; ++i) {
      s0v[i] = __builtin_amdgcn_exp2f(s0v[i] - m_run);
      sum += s0v[i];
    }
#pragma unroll
    for (int i = 0; i < 16; ++i) {
      s1v[i] = __builtin_amdgcn_exp2f(s1v[i] - m_run);
      sum += s1v[i];
    }
    sum += __shfl_xor(sum, 32);
    l_run += sum;
    bf16x8 pa[4];
#pragma unroll
    for (int g = 0; g < 2; ++g) {
      const f32x16& s = g ? s1v : s0v;
#pragma unroll
      for (int half = 0; half < 2; ++half) {
        int o = half * 8;
        uint32_t a0, a1, b0, b1;
        asm("v_cvt_pk_bf16_f32 %0, %1, %2" : "=v"(a0) : "v"(s[o + 0]), "v"(s[o + 1]));
        asm("v_cvt_pk_bf16_f32 %0, %1, %2" : "=v"(a1) : "v"(s[o + 2]), "v"(s[o + 3]));
        asm("v_cvt_pk_bf16_f32 %0, %1, %2" : "=v"(b0) : "v"(s[o + 4]), "v"(s[o + 5]));
        asm("v_cvt_pk_bf16_f32 %0, %1, %2" : "=v"(b1) : "v"(s[o + 6]), "v"(s[o + 7]));
        asm("v_permlane32_swap_b32 %0, %1" : "+v"(a0), "+v"(b0));
        asm("v_permlane32_swap_b32 %0, %1" : "+v"(a1), "+v"(b1));
        u32x4 w;
        w[0] = a0; w[1] = a1; w[2] = b0; w[3] = b1;
        pa[g * 2 + half] = __builtin_bit_cast(bf16x8, w);
      }
    }
    const u16* vb = Vs[cur];
    __builtin_amdgcn_s_setprio(1);
#pragma unroll
    for (int ks = 0; ks < 4; ++ks) {
      int blk = 2 * ks + hi;
      bf16x8 vf0 = *(const bf16x8*)(vb + l31 * 64 + ((blk ^ sw) * 8));
      bf16x8 vf1 = *(const bf16x8*)(vb + (32 + l31) * 64 + ((blk ^ sw) * 8));
      acc0 = __builtin_amdgcn_mfma_f32_32x32x16_bf16(pa[ks], vf0, acc0, 0, 0, 0);
      acc1 = __builtin_amdgcn_mfma_f32_32x32x16_bf16(pa[ks], vf1, acc1, 0, 0, 0);
    }
    __builtin_amdgcn_s_setprio(0);
    __syncthreads();
  }
  float linv = 1.0f / l_run;
  u16* cb = ctx + (size_t)(b * Sq + q0) * 1024 + h * 64;
#pragma unroll
  for (int r = 0; r < 16; ++r) {
    int src = (r & 3) + 8 * (r >> 2) + 4 * hi;
    float li = __shfl(linv, src);
    cb[(size_t)src * 1024 + l31] = f2bf(acc0[r] * li);
    cb[(size_t)src * 1024 + 32 + l31] = f2bf(acc1[r] * li);
  }
}

extern "C" void kernel_launch(void* const* d_in, const int* in_sizes, int n_in,
                              void* d_out, int out_size, void* d_ws, size_t ws_size,
                              hipStream_t stream) {
  const float* v = (const float*)d_in[0];
  const float* l = (const float*)d_in[1];
  const float* ln_v_g = (const float*)d_in[2];
  const float* ln_v_b = (const float*)d_in[3];
  const float* ln_l_g = (const float*)d_in[4];
  const float* ln_l_b = (const float*)d_in[5];
  const float* gamma_v = (const float*)d_in[6];
  const float* gamma_l = (const float*)d_in[7];
  const float* Wf[8];
  const float* Bf[8];
  for (int i = 0; i < 8; ++i) {
    Wf[i] = (const float*)d_in[8 + 2 * i];
    Bf[i] = (const float*)d_in[9 + 2 * i];
  }
  float* v_out = (float*)d_out;
  float* l_out = v_out + (size_t)16384 * 1024;

  char* p = (char*)d_ws;
  auto alloc = [&](size_t bytes) {
    char* r = p;
    p += (bytes + 255) & ~(size_t)255;
    return r;
  };
  u16* Wbf[8];
  for (int i = 0; i < 8; ++i) Wbf[i] = (u16*)alloc((size_t)1024 * 1024 * 2);
  u16* vn   = (u16*)alloc((size_t)16384 * 1024 * 2);  // LN(v)
  u16* lnm  = (u16*)alloc((size_t)4096 * 1024 * 2);   // LN(l)
  u16* bufA = (u16*)alloc((size_t)16384 * 1024 * 2);  // Q_v2l -> ctx_v (in-place)
  u16* bufB = (u16*)alloc((size_t)4096 * 1024 * 2);   // Q_l2v -> ctx_l (in-place)
  u16* bufC = (u16*)alloc((size_t)4096 * 1024 * 2);   // Vt_v2l
  u16* bufD = (u16*)alloc((size_t)16384 * 1024 * 2);  // Vt_l2v
  u16* bufF = (u16*)alloc((size_t)4096 * 1024 * 2);   // K_v2l
  u16* bufG = (u16*)alloc((size_t)16384 * 1024 * 2);  // K_l2v

  const float QSC = 0.125f * 1.4426950408889634f;  // 1/sqrt(64) * log2(e)
  Seg zs = {};

  cvt8_kernel<<<dim3(1024, 8), 256, 0, stream>>>(
      (const float4*)Wf[0], (const float4*)Wf[1], (const float4*)Wf[2], (const float4*)Wf[3],
      (const float4*)Wf[4], (const float4*)Wf[5], (const float4*)Wf[6], (const float4*)Wf[7],
      (ushort4*)Wbf[0], (ushort4*)Wbf[1], (ushort4*)Wbf[2], (ushort4*)Wbf[3],
      (ushort4*)Wbf[4], (ushort4*)Wbf[5], (ushort4*)Wbf[6], (ushort4*)Wbf[7]);
  ln_kernel<<<16384, 256, 0, stream>>>(v, ln_v_g, ln_v_b, vn);
  ln_kernel<<<4096, 256, 0, stream>>>(l, ln_l_g, ln_l_b, lnm);

  // grouped GEMM #1: trio0 on lnm (Q_l2v | K_v2l | Vt_v2l), trio1 on vn (Q_v2l | K_l2v | Vt_l2v)
  {
    Seg a = {Wbf[4], Bf[4], bufB, nullptr, nullptr, nullptr, 0, 0, QSC};
    Seg b = {Wbf[1], Bf[1], bufF, nullptr, nullptr, nullptr, 0, 0, 1.0f};
    Seg c = {Wbf[2], Bf[2], bufC, nullptr, nullptr, nullptr, 2, 9, 1.0f};
    Seg q = {Wbf[0], Bf[0], bufA, nullptr, nullptr, nullptr, 0, 0, QSC};
    Seg k = {Wbf[5], Bf[5], bufG, nullptr, nullptr, nullptr, 0, 0, 1.0f};
    Seg vv = {Wbf[6], Bf[6], bufD, nullptr, nullptr, nullptr, 2, 11, 1.0f};
    gemm_v8<<<dim3(768 + 3072), 256, 0, stream>>>(lnm, a, b, c, 32, 24,
                                                  vn, q, k, vv, 128, 24);
  }
  // merged attention: l2v (512 long blocks) FIRST, then v2l (2048 short blocks)
  attn2_kernel<<<dim3(512 + 2048), 256, 0, stream>>>(
      bufB, bufG, bufD, bufB, 512, 2048, 2, 512,
      bufA, bufF, bufC, bufA, 2048, 512, 4);
  // grouped GEMM #2: O-proj v (ctx_v) + O-proj l (ctx_l), fused residual epilogues
  {
    Seg ov = {Wbf[3], Bf[3], nullptr, v_out, v, gamma_v, 1, 0, 1.0f};
    Seg ol = {Wbf[7], Bf[7], nullptr, l_out, l, gamma_l, 1, 0, 1.0f};
    gemm_v8<<<dim3(1024 + 256), 256, 0, stream>>>(bufA, ov, zs, zs, 128, 8,
                                                  bufB, ol, zs, zs, 32, 8);
  }
}